// Round 10
// baseline (23.407 us; speedup 1.0000x reference)
//
#include <hip/hip_runtime.h>

// KAConv: out[b,f,h,w] = sum_{c,p} P_fcp(v) / (1 + |Q_fcp(v)|),
//   v = x[b,c,h+i-1,w+j-1] (zero pad), p = i*3+j
// Shapes: x[4,16,64,64], A[16,16,9,6], Bc[16,16,9,4], out[4,16,64,64], f32.
//
// Round 10: f-loop moved INSIDE the kernel. r2's counters showed the real
// stream is ~6350 lane-instrs/thread (~60% addressing/bounds/load overhead),
// and every prior round re-did window loads+masks once PER f (16x redundant).
// Now: block = 16 waves = 16 channels x one image row; each thread loads its
// 3x3 window ONCE (9 loads + masks, prologue), then loops f=0..15 over pure
// math (108 VALU/f) with per-f partials written straight to LDS (no runtime
// register indexing). One barrier, conflict-free c-reduction, coalesced
// store. Stream shrinks ~3.5x; coefficient s_loads stay on the scalar pipe
// (proven ~free in r8).

#define BB   4
#define CIN  16
#define COUT 16
#define HH   64
#define WW   64

__global__ __launch_bounds__(1024, 4) void KAConv_kernel(
    const float* __restrict__ x,    // [B,C,H,W]
    const float* __restrict__ A,    // [F,C,9,6]
    const float* __restrict__ Bc,   // [F,C,9,4]
    float* __restrict__ out)        // [B,F,H,W]
{
    // grid = b(4) x row(64) = 256 blocks; block = 1024 thr = 16 waves.
    const int blk = blockIdx.x;
    const int row = blk & 63;
    const int b   = blk >> 6;

    const int tid = threadIdx.x;
    const int c   = __builtin_amdgcn_readfirstlane(tid >> 6);  // wave = channel
    const int w   = tid & 63;                                  // lane = column

    __shared__ float sRed[CIN][COUT][WW];   // 64 KB: [c][f][px] partials

    // ---- Prologue: this thread's 3x3 window, loaded once ----
    const float* __restrict__ xc = x + (b * CIN + c) * (HH * WW);
    float win[3][3];
    #pragma unroll
    for (int i = 0; i < 3; ++i) {
        const int hh   = row - 1 + i;
        const bool okh = (hh >= 0) & (hh < HH);
        #pragma unroll
        for (int j = 0; j < 3; ++j) {
            const int wj  = w - 1 + j;
            const bool ok = okh & (wj >= 0) & (wj < WW);
            win[i][j] = ok ? xc[hh * WW + wj] : 0.0f;
        }
    }

    // ---- f-loop: pure math + uniform s_loads; partial -> LDS per f ----
    #pragma unroll 1
    for (int f = 0; f < COUT; ++f) {
        const float* __restrict__ Ac = A  + (f * CIN + c) * 54;  // s_load
        const float* __restrict__ Bq = Bc + (f * CIN + c) * 36;  // s_load

        float facc = 0.0f;
        #pragma unroll
        for (int p = 0; p < 9; ++p) {
            const float v = win[p / 3][p % 3];
            const float a0 = Ac[p*6+0], a1 = Ac[p*6+1], a2 = Ac[p*6+2];
            const float a3 = Ac[p*6+3], a4 = Ac[p*6+4], a5 = Ac[p*6+5];
            const float b1 = Bq[p*4+0], b2 = Bq[p*4+1];
            const float b3 = Bq[p*4+2], b4 = Bq[p*4+3];

            float P = a5;
            P = fmaf(P, v, a4); P = fmaf(P, v, a3); P = fmaf(P, v, a2);
            P = fmaf(P, v, a1); P = fmaf(P, v, a0);

            float q = b4;
            q = fmaf(q, v, b3); q = fmaf(q, v, b2); q = fmaf(q, v, b1);
            q *= v;

            const float d = 1.0f + fabsf(q);
            facc = fmaf(P, __builtin_amdgcn_rcpf(d), facc);
        }
        sRed[c][f][w] = facc;   // lanes consecutive -> conflict-free
    }
    __syncthreads();

    // ---- Reduce over c: thread t -> (f = t>>6, px = t&63) ----
    {
        const int f  = tid >> 6;
        const int px = tid & 63;
        float s = 0.0f;
        #pragma unroll
        for (int k = 0; k < CIN; ++k) s += sRed[k][f][px];  // stride-1 per instr
        out[((b * COUT + f) * HH + row) * WW + px] = s;     // coalesced
    }
}

extern "C" void kernel_launch(void* const* d_in, const int* in_sizes, int n_in,
                              void* d_out, int out_size, void* d_ws, size_t ws_size,
                              hipStream_t stream) {
    const float* x  = (const float*)d_in[0];
    const float* A  = (const float*)d_in[1];
    const float* Bc = (const float*)d_in[2];
    float* out = (float*)d_out;

    const int grid = BB * HH;   // 256 blocks, 1 per CU
    KAConv_kernel<<<grid, 1024, 0, stream>>>(x, A, Bc, out);
}